// Round 4
// baseline (2133.585 us; speedup 1.0000x reference)
//
#include <hip/hip_runtime.h>

#define T_STEPS 512
#define OUT_HFOFF ((size_t)134217728)              // T*B*H
#define OUT_CFOFF (OUT_HFOFF + (size_t)262144)     // + B*H

typedef short s8v  __attribute__((ext_vector_type(8)));   // 8 bf16 (4 VGPRs)
typedef float f32x4 __attribute__((ext_vector_type(4)));

static __device__ __forceinline__ unsigned short f2bf(float f){
  unsigned int x = __float_as_uint(f);
  x += 0x7fffu + ((x >> 16) & 1u);                 // RTNE
  return (unsigned short)(x >> 16);
}
static __device__ __forceinline__ float bf2f(unsigned short u){
  return __uint_as_float(((unsigned int)u) << 16);
}
static __device__ __forceinline__ float sigmoidf_(float x){
  return 1.f / (1.f + __expf(-x));
}
static __device__ __forceinline__ float tanhf_(float x){
  float e = __expf(2.f * x);
  return 1.f - 2.f / (e + 1.f);                    // correct limits at +-inf
}

// ---------------------------------------------------------------------------
// Prep: repack weights into bf16 MFMA B-fragment layouts.
//  W1x (hi+lo): [kk 16][kg 4][c 128][e 8]   (k = 32*kk+8*kg+e, c = g*32+j)
//  W1h (single):[kk 16][kg 4][c 128][e 8]
//  W2  (single):[g 4][hc 512][kg 4][e 8]    (j = 8*kg+e)
// ---------------------------------------------------------------------------
__global__ void prep_kernel(const float* __restrict__ W1, const float* __restrict__ W2,
                            unsigned short* __restrict__ wxhi, unsigned short* __restrict__ wxlo,
                            unsigned short* __restrict__ w1h, unsigned short* __restrict__ w2f)
{
  unsigned u = blockIdx.x * 256u + threadIdx.x;    // 0..65535
  {
    unsigned e = u & 7u, c = (u >> 3) & 127u, kg = (u >> 10) & 3u, kk = u >> 12;
    unsigned k = 32u*kk + 8u*kg + e;
    unsigned g = c >> 5, j = c & 31u;
    float v = W1[((size_t)g*1024u + k)*32u + j];
    unsigned short hi = f2bf(v);
    wxhi[u] = hi;
    wxlo[u] = f2bf(v - bf2f(hi));
    w1h[u]  = f2bf(W1[((size_t)g*1024u + 512u + k)*32u + j]);
  }
  {
    unsigned e = u & 7u, kg = (u >> 3) & 3u, hc = (u >> 5) & 511u, g = u >> 14;
    w2f[u] = f2bf(W2[((size_t)g*32u + 8u*kg + e)*512u + hc]);
  }
}

// ---------------------------------------------------------------------------
// Xproj = x @ W1x + b1, fp32-accurate via 3-mult bf16 split.
// M = T*B = 262144 (128/block), K = 512, N = 128.
// Output goes into out[t][b0][r*128 + c] (first 256 floats of each even row's
// slot) -- read then overwritten by rec_kernel at step t.
// ---------------------------------------------------------------------------
__global__ __launch_bounds__(256, 2) void xproj_kernel(
    const float* __restrict__ x, const unsigned short* __restrict__ wxhi,
    const unsigned short* __restrict__ wxlo, const float* __restrict__ b1,
    float* __restrict__ out)
{
  __shared__ unsigned short Ahi[128*40];   // [row][k] bf16, pad 40 vs 32
  __shared__ unsigned short Alo[128*40];
  const int tid = threadIdx.x;
  const int lane = tid & 63, wv = tid >> 6;
  const int l15 = lane & 15, lg = lane >> 4;
  const int wm = wv >> 1, wn = wv & 1;
  const int m0 = blockIdx.x * 128;
  const int tstep = m0 >> 9;
  const int brow0 = m0 & 511;

  f32x4 acc[4][4];
  #pragma unroll
  for (int i = 0; i < 4; ++i)
    #pragma unroll
    for (int j = 0; j < 4; ++j){ acc[i][j][0]=0.f; acc[i][j][1]=0.f; acc[i][j][2]=0.f; acc[i][j][3]=0.f; }

  float b1v[4];
  #pragma unroll
  for (int nt = 0; nt < 4; ++nt) b1v[nt] = b1[64*wn + 16*nt + l15];

  const int srow = tid >> 1;          // 0..127
  const int sk   = (tid & 1) * 16;    // 0 or 16

  for (int kk = 0; kk < 16; ++kk){
    __syncthreads();
    // stage A tile [128 rows][32 k] -> bf16 hi/lo in LDS
    const float* src = x + (size_t)(m0 + srow)*512 + kk*32 + sk;
    float fv[16];
    #pragma unroll
    for (int i = 0; i < 4; ++i){
      float4 v = *(const float4*)(src + 4*i);
      fv[4*i+0]=v.x; fv[4*i+1]=v.y; fv[4*i+2]=v.z; fv[4*i+3]=v.w;
    }
    #pragma unroll
    for (int i = 0; i < 8; ++i){
      float a0 = fv[2*i], a1 = fv[2*i+1];
      unsigned short h0 = f2bf(a0), h1 = f2bf(a1);
      unsigned short q0 = f2bf(a0 - bf2f(h0)), q1 = f2bf(a1 - bf2f(h1));
      *(unsigned int*)&Ahi[srow*40 + sk + 2*i] = (unsigned)h0 | ((unsigned)h1 << 16);
      *(unsigned int*)&Alo[srow*40 + sk + 2*i] = (unsigned)q0 | ((unsigned)q1 << 16);
    }
    __syncthreads();

    s8v ah[4], al[4], bh[4], bl[4];
    #pragma unroll
    for (int mt = 0; mt < 4; ++mt){
      int off = (64*wm + 16*mt + l15)*40 + 8*lg;
      ah[mt] = *(const s8v*)&Ahi[off];
      al[mt] = *(const s8v*)&Alo[off];
    }
    #pragma unroll
    for (int nt = 0; nt < 4; ++nt){
      size_t idx = ((size_t)(kk*4 + lg)*128 + (64*wn + 16*nt + l15)) * 8;
      bh[nt] = *(const s8v*)&wxhi[idx];
      bl[nt] = *(const s8v*)&wxlo[idx];
    }
    #pragma unroll
    for (int mt = 0; mt < 4; ++mt)
      #pragma unroll
      for (int nt = 0; nt < 4; ++nt){
        acc[mt][nt] = __builtin_amdgcn_mfma_f32_16x16x32_bf16(ah[mt], bh[nt], acc[mt][nt], 0,0,0);
        acc[mt][nt] = __builtin_amdgcn_mfma_f32_16x16x32_bf16(ah[mt], bl[nt], acc[mt][nt], 0,0,0);
        acc[mt][nt] = __builtin_amdgcn_mfma_f32_16x16x32_bf16(al[mt], bh[nt], acc[mt][nt], 0,0,0);
      }
  }

  // epilogue: C/D layout col=lane&15, row=4*(lane>>4)+r  [m89-verified]
  #pragma unroll
  for (int mt = 0; mt < 4; ++mt)
    #pragma unroll
    for (int nt = 0; nt < 4; ++nt){
      int c = 64*wn + 16*nt + l15;
      #pragma unroll
      for (int r = 0; r < 4; ++r){
        int b = brow0 + 64*wm + 16*mt + 4*lg + r;
        size_t o = ((size_t)(tstep*512 + (b & ~1)))*512 + (size_t)(b & 1)*128 + c;
        out[o] = acc[mt][nt][r] + b1v[nt];
      }
    }
}

// ---------------------------------------------------------------------------
// Recurrent kernel: 256 independent persistent blocks, 2 batch rows each,
// 4 waves, weights register-resident as bf16 B-fragments. No grid sync.
// 2 barriers/step (gatesS write->read is same-wave: wave wv writes cols
// [128wv,128wv+128), its threads read col2=2*tid in that same range).
// ---------------------------------------------------------------------------
__global__ __launch_bounds__(256, 1) void rec_kernel(
    const float* __restrict__ hx, const float* __restrict__ cx,
    const float* __restrict__ b2, const unsigned short* __restrict__ w1hf,
    const unsigned short* __restrict__ w2f, float* __restrict__ out)
{
  // A-fragment-ordered LDS: block (kk*4+kg) of 288B = [16 rows][8 e]*2B + 32B pad
  __shared__ unsigned short hbuf[64*144];   // h  [16 rows][512 k] bf16 (2 real rows)
  __shared__ unsigned short z1buf[16*144];  // z1 [4 g][16 rows][32 j] bf16
  __shared__ float gatesS[8*512];           // [g 4][r 2][col 512] f32 (pre-bias)

  const int tid = threadIdx.x;
  const int lane = tid & 63, wv = tid >> 6;
  const int l15 = lane & 15, lg = lane >> 4;
  const int b0 = blockIdx.x * 2;
  const int col2 = tid * 2;                 // pointwise owns cols col2, col2+1

  // ---- load weight fragments into registers ----
  s8v w1h[16][2];                           // wave's 32 z1-cols, K=512
  #pragma unroll
  for (int kk = 0; kk < 16; ++kk)
    #pragma unroll
    for (int nt = 0; nt < 2; ++nt){
      size_t idx = ((size_t)(kk*4 + lg)*128 + (32*wv + 16*nt + l15)) * 8;
      w1h[kk][nt] = *(const s8v*)&w1hf[idx];
    }
  s8v w2r[4][8];                            // wave's 128 h-cols, 4 gates, K=32
  #pragma unroll
  for (int g = 0; g < 4; ++g)
    #pragma unroll
    for (int nt = 0; nt < 8; ++nt){
      size_t idx = ((size_t)(g*512 + (128*wv + 16*nt + l15))*4 + lg) * 8;
      w2r[g][nt] = *(const s8v*)&w2f[idx];
    }

  float creg[2][2], hreg[2][2], b2r[4][2];
  #pragma unroll
  for (int r = 0; r < 2; ++r){
    creg[r][0] = cx[(size_t)(b0+r)*512 + col2];
    creg[r][1] = cx[(size_t)(b0+r)*512 + col2 + 1];
    hreg[r][0] = 0.f; hreg[r][1] = 0.f;
  }
  #pragma unroll
  for (int g = 0; g < 4; ++g){
    b2r[g][0] = b2[(size_t)g*512 + col2];
    b2r[g][1] = b2[(size_t)g*512 + col2 + 1];
  }

  // ---- init hbuf: zero (pad rows stay 0 forever), then write h0 ----
  for (int i = tid; i < 64*144; i += 256) hbuf[i] = 0;
  __syncthreads();
  {
    const int kk = col2 >> 5, kg = (col2 >> 3) & 3, e = col2 & 7;   // e even -> 4B aligned
    char* base = (char*)hbuf + (kk*4 + kg)*288 + e*2;
    #pragma unroll
    for (int r = 0; r < 2; ++r){
      float h0v = hx[(size_t)(b0+r)*512 + col2];
      float h1v = hx[(size_t)(b0+r)*512 + col2 + 1];
      *(unsigned int*)(base + r*16) = (unsigned)f2bf(h0v) | ((unsigned)f2bf(h1v) << 16);
    }
  }
  __syncthreads();

  // ---- xp software pipeline: preload step 0 ----
  float xp[2][2] = {{0.f,0.f},{0.f,0.f}};
  if (lg == 0){
    const float* xb = out + ((size_t)b0)*512;
    #pragma unroll
    for (int nt = 0; nt < 2; ++nt)
      #pragma unroll
      for (int r = 0; r < 2; ++r)
        xp[nt][r] = xb[r*128 + 32*wv + 16*nt + l15];
  }

  for (int ts = 0; ts < T_STEPS; ++ts){
    // ---- prefetch Xproj for step ts+1 (consumed next iteration) ----
    float xpn[2][2] = {{0.f,0.f},{0.f,0.f}};
    if (lg == 0 && ts + 1 < T_STEPS){
      const float* xb = out + ((size_t)((ts+1)*512 + b0))*512;
      #pragma unroll
      for (int nt = 0; nt < 2; ++nt)
        #pragma unroll
        for (int r = 0; r < 2; ++r)
          xpn[nt][r] = xb[r*128 + 32*wv + 16*nt + l15];
    }

    // ---- GEMM1: z1_pre = h @ W1h (wave owns 32 cols) ----
    f32x4 acc0; acc0[0]=0.f; acc0[1]=0.f; acc0[2]=0.f; acc0[3]=0.f;
    f32x4 acc1 = acc0;
    #pragma unroll
    for (int kk = 0; kk < 16; ++kk){
      s8v af = *(const s8v*)((char*)hbuf + (kk*4 + lg)*288 + l15*16);
      acc0 = __builtin_amdgcn_mfma_f32_16x16x32_bf16(af, w1h[kk][0], acc0, 0,0,0);
      acc1 = __builtin_amdgcn_mfma_f32_16x16x32_bf16(af, w1h[kk][1], acc1, 0,0,0);
    }
    // z1 = relu(acc + Xproj) -> bf16 A-fragment layout in LDS
    #pragma unroll
    for (int nt = 0; nt < 2; ++nt){
      f32x4 a = nt ? acc1 : acc0;
      int cz = 32*wv + 16*nt + l15;
      int g = cz >> 5, j = cz & 31;
      char* zb = (char*)z1buf + (g*4 + (j>>3))*288 + (j&7)*2;
      #pragma unroll
      for (int rr = 0; rr < 4; ++rr){
        float v = a[rr];
        if (lg == 0 && rr < 2) v += xp[nt][rr];
        v = fmaxf(v, 0.f);
        *(unsigned short*)(zb + (4*lg + rr)*16) = f2bf(v);
      }
    }
    __syncthreads();                        // barrier 1: z1buf cross-wave

    // ---- GEMM2: gates = z1 @ W2 (wave owns 128 h-cols, all 4 gates) ----
    s8v zf[4];
    #pragma unroll
    for (int g = 0; g < 4; ++g)
      zf[g] = *(const s8v*)((char*)z1buf + (g*4 + lg)*288 + l15*16);
    f32x4 z4; z4[0]=0.f; z4[1]=0.f; z4[2]=0.f; z4[3]=0.f;
    #pragma unroll
    for (int nt = 0; nt < 8; ++nt){
      f32x4 ga[4];
      #pragma unroll
      for (int g = 0; g < 4; ++g)
        ga[g] = __builtin_amdgcn_mfma_f32_16x16x32_bf16(zf[g], w2r[g][nt], z4, 0,0,0);
      if (lg == 0){
        int c = 128*wv + 16*nt + l15;
        #pragma unroll
        for (int g = 0; g < 4; ++g){
          gatesS[(g*2 + 0)*512 + c] = ga[g][0];
          gatesS[(g*2 + 1)*512 + c] = ga[g][1];
        }
      }
    }
    // no barrier: gatesS producer wave == consumer wave (lgkmcnt suffices)

    // ---- pointwise (each thread owns 2 cols x 2 rows, same-wave data) ----
    #pragma unroll
    for (int r = 0; r < 2; ++r){
      #pragma unroll
      for (int i = 0; i < 2; ++i){
        int c = col2 + i;
        float F = sigmoidf_(gatesS[(0*2 + r)*512 + c] + b2r[0][i]);
        float I = sigmoidf_(gatesS[(1*2 + r)*512 + c] + b2r[1][i]);
        float G = tanhf_  (gatesS[(2*2 + r)*512 + c] + b2r[2][i]);
        float O = sigmoidf_(gatesS[(3*2 + r)*512 + c] + b2r[3][i]);
        float cn = F*creg[r][i] + I*G;
        float hn = O*tanhf_(cn);
        creg[r][i] = cn; hreg[r][i] = hn;
      }
      float2 st; st.x = hreg[r][0]; st.y = hreg[r][1];
      *(float2*)(out + ((size_t)(ts*512 + b0 + r))*512 + col2) = st;
      const int kk = col2 >> 5, kg = (col2 >> 3) & 3, e = col2 & 7;
      *(unsigned int*)((char*)hbuf + (kk*4 + kg)*288 + r*16 + e*2) =
          (unsigned)f2bf(hreg[r][0]) | ((unsigned)f2bf(hreg[r][1]) << 16);
    }
    __syncthreads();                        // barrier 2: hbuf/z1buf for next step

    #pragma unroll
    for (int nt = 0; nt < 2; ++nt)
      #pragma unroll
      for (int r = 0; r < 2; ++r)
        xp[nt][r] = xpn[nt][r];
  }

  // ---- hf, cf ----
  #pragma unroll
  for (int r = 0; r < 2; ++r){
    float2 hv; hv.x = hreg[r][0]; hv.y = hreg[r][1];
    *(float2*)(out + OUT_HFOFF + (size_t)(b0+r)*512 + col2) = hv;
    float2 cv; cv.x = creg[r][0]; cv.y = creg[r][1];
    *(float2*)(out + OUT_CFOFF + (size_t)(b0+r)*512 + col2) = cv;
  }
}

extern "C" void kernel_launch(void* const* d_in, const int* in_sizes, int n_in,
                              void* d_out, int out_size, void* d_ws, size_t ws_size,
                              hipStream_t stream)
{
  const float* x   = (const float*)d_in[0];   // [512,512,512]
  const float* hx  = (const float*)d_in[1];   // [512,512]
  const float* cx  = (const float*)d_in[2];   // [512,512]
  const float* W1  = (const float*)d_in[3];   // [4,1024,32]
  const float* b1  = (const float*)d_in[4];   // [4,32]
  const float* W2  = (const float*)d_in[5];   // [4,32,512]
  const float* b2  = (const float*)d_in[6];   // [4,512]
  float* out = (float*)d_out;

  unsigned short* wsb  = (unsigned short*)d_ws;   // 4 x 65536 bf16 = 512 KB
  unsigned short* wxhi = wsb;
  unsigned short* wxlo = wsb + 65536;
  unsigned short* w1h  = wsb + 131072;
  unsigned short* w2f  = wsb + 196608;

  prep_kernel <<<256, 256, 0, stream>>>(W1, W2, wxhi, wxlo, w1h, w2f);
  xproj_kernel<<<2048, 256, 0, stream>>>(x, wxhi, wxlo, b1, out);
  rec_kernel  <<<256, 256, 0, stream>>>(hx, cx, b2, w1h, w2f, out);
}